// Round 1
// baseline (79.715 us; speedup 1.0000x reference)
//
#include <hip/hip_runtime.h>
#include <math.h>

#define BATCH   256
#define MAXSTEP 200
#define NQ      1024
#define SM1     199            // MAX_STEP - 1
#define NROWS   (BATCH * SM1)  // 50944
#define NTHR    1024           // 16 waves per block, one block per student
#define NWAVE   16
#define NV4     (SM1 * 512)    // v4f elements in one student's scanned region (101888)

typedef float v4f __attribute__((ext_vector_type(4)));

// One 1024-thread block per student b.
// Phase 1: 16 waves stream rows s=1..199 (contiguous 1.63 MB) at v4f granularity.
//          batch is one-hot per row (value exactly 1.0, or all-zero when padded),
//          so at most ONE lane in the whole region hits per row -> race-free
//          plain LDS store of the hot column index. No reduces in the hot loop.
// Phase 2 (same block, LDS-resident): p[b,i] = pred[b,i,col&1023], a = (col<NQ),
//          last = max{i : p>0} (p>0 iff row valid), BCE with log clamp, one
//          atomicAdd of the per-student mean into out[0] (zeroed by memset node).
__global__ __launch_bounds__(NTHR, 1) void k_fused(const float* __restrict__ pred,
                                                   const float* __restrict__ batch,
                                                   float* __restrict__ out) {
    const int b    = blockIdx.x;
    const int t    = threadIdx.x;
    const int lane = t & 63;
    const int wid  = t >> 6;

    __shared__ int   s_hq[SM1];     // hot column (0..2047) per row, -1 if padded
    __shared__ int   s_red[NWAVE];
    __shared__ float s_sum[NWAVE];
    __shared__ int   s_last;

    if (t < SM1) s_hq[t] = -1;
    __syncthreads();

    const v4f* base = (const v4f*)(batch + ((size_t)b * MAXSTEP + 1) * (2 * NQ));

#define SCAN_BODY(GG)                                                  \
    {                                                                  \
        v4f v = __builtin_nontemporal_load(base + (GG));               \
        float sm = (v[0] + v[1]) + (v[2] + v[3]);                      \
        if (sm != 0.f) {               /* rare: ~199 hits / 101888 */  \
            int j = 0;                                                 \
            if (v[1] != 0.f) j = 1;                                    \
            if (v[2] != 0.f) j = 2;                                    \
            if (v[3] != 0.f) j = 3;                                    \
            int f = ((GG) << 2) + j;   /* float index in region */     \
            s_hq[f >> 11] = f & 2047;  /* row = f/2048, col = f%2048 */\
        }                                                              \
    }

    int g = t;
    #pragma unroll 8
    for (int k = 0; k < 96; ++k, g += NTHR) {   // 96*1024 = 98304 v4f, unconditional
        SCAN_BODY(g)
    }
    #pragma unroll
    for (int k = 0; k < 4; ++k, g += NTHR) {    // remainder up to 101888 (wave-uniform cond)
        if (g < NV4) SCAN_BODY(g)
    }
#undef SCAN_BODY

    __syncthreads();

    // ---- tail, fully in-block ----
    const bool th = (t < SM1);
    int hq = th ? s_hq[t] : -1;
    float p = 0.f, a = 0.f;
    if (hq >= 0) {
        p = pred[((size_t)b * MAXSTEP + t) * NQ + (hq & (NQ - 1))];
        a = (hq < NQ) ? 1.f : 0.f;
    }
    if (th) {
        out[1 + b * SM1 + t]         = p;   // prediction (coalesced)
        out[1 + NROWS + b * SM1 + t] = a;   // ground_truth
    }

    // last valid index: max i with p > 0 (pred strictly in (1e-4, 1-1e-4))
    int m = (th && p > 0.f) ? t : -1;
    #pragma unroll
    for (int off = 32; off > 0; off >>= 1) m = max(m, __shfl_xor(m, off));
    if (lane == 0) s_red[wid] = m;
    __syncthreads();
    if (t == 0) {
        int mm = -1;
        #pragma unroll
        for (int w = 0; w < NWAVE; ++w) mm = max(mm, s_red[w]);
        s_last = mm;
    }
    __syncthreads();
    const int last = s_last;

    float bce = 0.f;
    const bool valid = th && ((last < 0) || (t <= last));
    if (valid) {
        float logp = fmaxf(logf(p), -100.f);
        float log1 = fmaxf(logf(1.f - p), -100.f);
        bce = -(a * logp + (1.f - a) * log1);
    }
    float sum = bce;
    #pragma unroll
    for (int off = 32; off > 0; off >>= 1) sum += __shfl_xor(sum, off);
    if (lane == 0) s_sum[wid] = sum;
    __syncthreads();
    if (t == 0) {
        float total = 0.f;
        #pragma unroll
        for (int w = 0; w < NWAVE; ++w) total += s_sum[w];
        float cntf = (last >= 0) ? (float)(last + 1) : (float)SM1;
        atomicAdd(out, total / cntf);
    }
}

extern "C" void kernel_launch(void* const* d_in, const int* in_sizes, int n_in,
                              void* d_out, int out_size, void* d_ws, size_t ws_size,
                              hipStream_t stream) {
    const float* pred  = (const float*)d_in[0];
    const float* batch = (const float*)d_in[1];
    float* out = (float*)d_out;

    hipMemsetAsync(d_out, 0, sizeof(float), stream);      // zero loss accumulator
    k_fused<<<BATCH, NTHR, 0, stream>>>(pred, batch, out);
}